// Round 17
// baseline (287.782 us; speedup 1.0000x reference)
//
#include <hip/hip_runtime.h>
#include <hip/hip_bf16.h>

// ---------------------------------------------------------------------------
// TransformerLayer on MI355X (gfx950). Round 17 (= Round 16 resubmit; R16
// died pre-execution on the recurring dead container — source hash bumped via
// this comment only): faithful m201 8-phase 256x256 GEMM — 8 waves (2Mx4N),
// BK=64 as 2 K-half panels [256][32], 128 KB dbuf LDS, per phase {ds_read,
// stage 1 half-tile, barrier, lgkmcnt(0)+sched_barrier(0), setprio(1),
// 16 MFMA, setprio(0), barrier}, vmcnt(6) ONCE per K-tile (3 half-tiles in
// flight). Attn path / prep / reduces from R13-R15.
// ---------------------------------------------------------------------------

typedef __attribute__((ext_vector_type(4))) float  f32x4;
typedef __attribute__((ext_vector_type(8))) short  bf16x8;
typedef __attribute__((ext_vector_type(4))) unsigned short us4;
typedef __attribute__((ext_vector_type(8))) unsigned short us8;

#define DEVINL __device__ __forceinline__

static constexpr int S   = 4096;
static constexpr int DM  = 1024;
static constexpr int DI  = 4096;

DEVINL unsigned short f2bf(float f) {
  union { float f; unsigned u; } v; v.f = f;
  unsigned r = v.u + 0x7fffu + ((v.u >> 16) & 1u);   // RNE
  return (unsigned short)(r >> 16);
}

DEVINL float bf2f(unsigned short b) {
  union { unsigned u; float f; } v; v.u = ((unsigned)b) << 16;
  return v.f;
}

DEVINL void gld_lds16(const unsigned short* g, unsigned short* l) {
  __builtin_amdgcn_global_load_lds(
      (const __attribute__((address_space(1))) void*)g,
      (__attribute__((address_space(3))) void*)l,
      16, 0, 0);
}

// bijective XCD remap (m204)
DEVINL int xcd_remap(int orig, int nwg) {
  const int q = nwg >> 3, r = nwg & 7;
  const int x = orig & 7, idx = orig >> 3;
  return (x < r ? x * (q + 1) : r * (q + 1) + (x - r) * q) + idx;
}

// ---------------------------------------------------------------------------
// Fused prep (unchanged)
// ---------------------------------------------------------------------------
__global__ void prep_all(const float* __restrict__ x,
                         const float* __restrict__ Wq,
                         const float* __restrict__ Wk,
                         const float* __restrict__ Wv,
                         const float* __restrict__ W1,
                         const float* __restrict__ W2,
                         const float* __restrict__ bq,
                         const float* __restrict__ bk,
                         const float* __restrict__ bv,
                         unsigned short* __restrict__ xb,
                         unsigned short* __restrict__ Wqkvt,
                         unsigned short* __restrict__ W1t,
                         unsigned short* __restrict__ W2t,
                         float* __restrict__ bqkv) {
  __shared__ float tile[32][33];
  const int b = blockIdx.x;
  const int tid = threadIdx.x;

  if (b < 2048) {                       // x -> xb
    long i = ((long)b * 256 + tid) * 8;
    f32x4 a = *(const f32x4*)(x + i);
    f32x4 c = *(const f32x4*)(x + i + 4);
    us8 o;
    o[0] = f2bf(a[0]); o[1] = f2bf(a[1]); o[2] = f2bf(a[2]); o[3] = f2bf(a[3]);
    o[4] = f2bf(c[0]); o[5] = f2bf(c[1]); o[6] = f2bf(c[2]); o[7] = f2bf(c[3]);
    *(us8*)(xb + i) = o;
    return;
  }
  if (b >= 13312) {                     // bias concat
    const int t = b - 13312;
    const float* src = (t == 0) ? bq : (t == 1) ? bk : bv;
    const int i = tid * 4;
    *(f32x4*)(bqkv + t * DM + i) = *(const f32x4*)(src + i);
    return;
  }

  const float* in; unsigned short* out; int R, C, t;
  if (b < 3072)      { in = Wq; out = Wqkvt;                      R = DM; C = DM; t = b - 2048; }
  else if (b < 4096) { in = Wk; out = Wqkvt + (size_t)DM * DM;    R = DM; C = DM; t = b - 3072; }
  else if (b < 5120) { in = Wv; out = Wqkvt + 2 * (size_t)DM * DM;R = DM; C = DM; t = b - 4096; }
  else if (b < 9216) { in = W1; out = W1t;                        R = DM; C = DI; t = b - 5120; }
  else               { in = W2; out = W2t;                        R = DI; C = DM; t = b - 9216; }
  const int gx = C >> 5;
  const int bx = (t % gx) * 32, by = (t / gx) * 32;
  const int tx = tid & 31, ty = tid >> 5;     // 32 x 8
  #pragma unroll
  for (int j = 0; j < 4; ++j) {
    int r = ty + j * 8;
    tile[r][tx] = in[(size_t)(by + r) * C + bx + tx];
  }
  __syncthreads();
  #pragma unroll
  for (int j = 0; j < 4; ++j) {
    int r = ty + j * 8;
    out[(size_t)(bx + r) * R + by + tx] = f2bf(tile[tx][r]);
  }
}

// bf16 [R][C] (row stride ld) -> out[c*ldo + r]
__global__ void transpose_bf16(const unsigned short* __restrict__ in, int ld,
                               unsigned short* __restrict__ out, int ldo) {
  __shared__ unsigned short tile[32][33];
  const int bx = blockIdx.x * 32, by = blockIdx.y * 32;
  const int tx = threadIdx.x, ty = threadIdx.y;
  #pragma unroll
  for (int j = 0; j < 4; ++j) {
    int r = ty + j * 8;
    tile[r][tx] = in[(size_t)(by + r) * ld + bx + tx];
  }
  __syncthreads();
  #pragma unroll
  for (int j = 0; j < 4; ++j) {
    int r = ty + j * 8;
    out[(size_t)(bx + r) * ldo + by + tx] = tile[tx][r];
  }
}

// ---------------------------------------------------------------------------
// 256x256 tile, 512 thr (8 waves, 2Mx4N), BK=64 as panels A_k0|B_k0|A_k1|B_k1
// ([256][32] each, swizzled), dbuf = 128 KB. 4 phases per K-tile; vmcnt(6)
// once per tile. C = A[M,K](lda) @ Bt[N,K](ldb)^T.
// ---------------------------------------------------------------------------
enum { EPI_QKV = 0, EPI_SCE = 1, EPI_FF1 = 4, EPI_PART = 6 };

#define VM_WAIT6 asm volatile("s_waitcnt vmcnt(6)" ::: "memory")
#define VM_WAIT0 asm volatile("s_waitcnt vmcnt(0)" ::: "memory")
#define LGKM0    do { asm volatile("s_waitcnt lgkmcnt(0)" ::: "memory"); \
                      __builtin_amdgcn_sched_barrier(0); } while (0)

template <int EPI, bool TRI_PACK, bool TRI_TRUNC>
__launch_bounds__(512, 2)
__global__ void gemm8p(const unsigned short* __restrict__ A,
                       const unsigned short* __restrict__ Bt,
                       int M, int N, int K, int lda, int ldb, int kChunk, int GX,
                       const float* __restrict__ bias,
                       float* __restrict__ Cf,
                       unsigned short* __restrict__ Cb,
                       float scale) {
  const int wg = xcd_remap(blockIdx.x, gridDim.x);
  int bm, bn;
  if (TRI_PACK) {
    int t = wg;
    bm = (int)((sqrtf(8.f * (float)t + 1.f) - 1.f) * 0.5f);
    while ((bm + 1) * (bm + 2) / 2 <= t) ++bm;
    while (bm * (bm + 1) / 2 > t) --bm;
    bn = t - bm * (bm + 1) / 2;
  } else { bm = wg / GX; bn = wg % GX; }
  const int bm0 = bm * 256, bn0 = bn * 256;

  const int kbeg = blockIdx.z * kChunk;
  int kend = min(K, kbeg + kChunk);
  if (TRI_TRUNC) kend = min(kend, bm0 + 256);
  const int NT = (kend > kbeg) ? ((kend - kbeg) >> 6) : 0;   // BK=64 tiles

  // 2 bufs x 4 panels x [256][32] bf16 (16 KB each) = 128 KB
  __shared__ __align__(16) unsigned short lds[2 * 32768];

  const int tid  = threadIdx.x;
  const int lane = tid & 63;
  const int w    = tid >> 6;                  // wave 0..7
  const int wr   = w >> 2, wc = w & 3;        // 2M x 4N wave grid
  const int fr   = lane & 15, fq = lane >> 4;

  f32x4 acc[8][4] = {};

  // ---- staging (pre-swizzled global source; linear LDS dest) ----
  const int srow   = tid >> 2;                               // 0..127
  const int swcolE = ((tid & 3) * 8) ^ ((srow & 6) << 2);    // swizzled col in K32
  const unsigned short* gA = A  + (size_t)(bm0 + srow) * lda + kbeg + swcolE;
  const unsigned short* gB = Bt + (size_t)(bn0 + srow) * ldb + kbeg + swcolE;
  const size_t aH = (size_t)128 * lda, bH = (size_t)128 * ldb;

  auto stA = [&](int buf, int t_, int ks) {   // panel A_ks of tile t_ (2 loads)
    unsigned short* dst = (unsigned short*)lds + buf * 32768 + ks * 16384 + w * 512;
    const size_t go = (size_t)t_ * 64 + ks * 32;
    gld_lds16(gA + go,      dst);             // rows 0-127
    gld_lds16(gA + aH + go, dst + 4096);      // rows 128-255
  };
  auto stB = [&](int buf, int t_, int ks) {
    unsigned short* dst = (unsigned short*)lds + buf * 32768 + 8192 + ks * 16384 + w * 512;
    const size_t go = (size_t)t_ * 64 + ks * 32;
    gld_lds16(gB + go,      dst);
    gld_lds16(gB + bH + go, dst + 4096);
  };

  // ---- fragment reads (swizzled) ----
  const int frSw = (fq * 8) ^ ((fr & 6) << 2);
  auto rdA = [&](int buf, int ks, int mi) {
    return *(const bf16x8*)((const unsigned short*)lds + buf * 32768 + ks * 16384 +
                            (wr * 128 + mi * 16 + fr) * 32 + frSw);
  };
  auto rdB = [&](int buf, int ks, int ni) {
    return *(const bf16x8*)((const unsigned short*)lds + buf * 32768 + 8192 + ks * 16384 +
                            (wc * 64 + ni * 16 + fr) * 32 + frSw);
  };

  if (NT > 0) {
    // prologue: tile0 fully; tile1 ht1-3 (A_k0,B_k0,A_k1); drain tile0
    stA(0, 0, 0); stB(0, 0, 0); stA(0, 0, 1); stB(0, 0, 1);
    if (NT > 1) { stA(1, 1, 0); stB(1, 1, 0); stA(1, 1, 1); VM_WAIT6; }
    else        { VM_WAIT0; }
    __builtin_amdgcn_s_barrier();

    for (int t = 0; t < NT; ++t) {
      const int buf = t & 1, nb = buf ^ 1;
      const bool p1ok = (t + 1 < NT), p2ok = (t + 2 < NT);
      bf16x8 a[8], b0, b1;

      // ---- phase 0: ks0, ni 0-1 ----
      #pragma unroll
      for (int mi = 0; mi < 8; ++mi) a[mi] = rdA(buf, 0, mi);
      b0 = rdB(buf, 0, 0); b1 = rdB(buf, 0, 1);
      if (p1ok) stB(nb, t + 1, 1);           // t+1.ht4 = B_k1
      __builtin_amdgcn_s_barrier();
      LGKM0;
      __builtin_amdgcn_s_setprio(1);
      #pragma unroll
      for (int mi = 0; mi < 8; ++mi) {
        acc[mi][0] = __builtin_amdgcn_mfma_f32_16x16x32_bf16(a[mi], b0, acc[mi][0], 0, 0, 0);
        acc[mi][1] = __builtin_amdgcn_mfma_f32_16x16x32_bf16(a[mi], b1, acc[mi][1], 0, 0, 0);
      }
      __builtin_amdgcn_s_setprio(0);
      __builtin_amdgcn_s_barrier();

      // ---- phase 1: ks0, ni 2-3 (A held) ----
      b0 = rdB(buf, 0, 2); b1 = rdB(buf, 0, 3);
      if (p2ok) stA(buf, t + 2, 0);          // t+2.ht1 = A_k0 (region dead after p0)
      __builtin_amdgcn_s_barrier();
      LGKM0;
      __builtin_amdgcn_s_setprio(1);
      #pragma unroll
      for (int mi = 0; mi < 8; ++mi) {
        acc[mi][2] = __builtin_amdgcn_mfma_f32_16x16x32_bf16(a[mi], b0, acc[mi][2], 0, 0, 0);
        acc[mi][3] = __builtin_amdgcn_mfma_f32_16x16x32_bf16(a[mi], b1, acc[mi][3], 0, 0, 0);
      }
      __builtin_amdgcn_s_setprio(0);
      __builtin_amdgcn_s_barrier();

      // ---- phase 2: ks1, ni 0-1 ----
      #pragma unroll
      for (int mi = 0; mi < 8; ++mi) a[mi] = rdA(buf, 1, mi);
      b0 = rdB(buf, 1, 0); b1 = rdB(buf, 1, 1);
      if (p2ok) stB(buf, t + 2, 0);          // t+2.ht2 = B_k0 (dead after p1)
      __builtin_amdgcn_s_barrier();
      LGKM0;
      __builtin_amdgcn_s_setprio(1);
      #pragma unroll
      for (int mi = 0; mi < 8; ++mi) {
        acc[mi][0] = __builtin_amdgcn_mfma_f32_16x16x32_bf16(a[mi], b0, acc[mi][0], 0, 0, 0);
        acc[mi][1] = __builtin_amdgcn_mfma_f32_16x16x32_bf16(a[mi], b1, acc[mi][1], 0, 0, 0);
      }
      __builtin_amdgcn_s_setprio(0);
      __builtin_amdgcn_s_barrier();

      // ---- phase 3: ks1, ni 2-3 ----
      b0 = rdB(buf, 1, 2); b1 = rdB(buf, 1, 3);
      if (p2ok) stA(buf, t + 2, 1);          // t+2.ht3 = A_k1 (dead after p2)
      __builtin_amdgcn_s_barrier();
      LGKM0;
      __builtin_amdgcn_s_setprio(1);
      #pragma unroll
      for (int mi = 0; mi < 8; ++mi) {
        acc[mi][2] = __builtin_amdgcn_mfma_f32_16x16x32_bf16(a[mi], b0, acc[mi][2], 0, 0, 0);
        acc[mi][3] = __builtin_amdgcn_mfma_f32_16x16x32_bf16(a[mi], b1, acc[mi][3], 0, 0, 0);
      }
      __builtin_amdgcn_s_setprio(0);
      if (p2ok)      { VM_WAIT6; }           // t+1 complete; t+2.ht1-3 in flight
      else if (p1ok) { VM_WAIT0; }           // tail: drain t+1 fully
      __builtin_amdgcn_s_barrier();
    }
  }

  // ---- epilogue: C/D layout col = lane&15, row = (lane>>4)*4 + reg ----
  const int row0 = bm0 + wr * 128 + fq * 4;
  const int col0 = bn0 + wc * 64 + fr;
  const size_t zoff = (EPI == EPI_PART) ? (size_t)blockIdx.z * M * N : 0;
  #pragma unroll
  for (int ni = 0; ni < 4; ++ni) {
    const int col = col0 + ni * 16;
    float bval = 0.f;
    if (EPI == EPI_QKV || EPI == EPI_FF1) bval = bias[col];
    #pragma unroll
    for (int mi = 0; mi < 8; ++mi) {
      #pragma unroll
      for (int j = 0; j < 4; ++j) {
        const int row = row0 + mi * 16 + j;
        const size_t idx = zoff + (size_t)row * N + col;
        const float c = acc[mi][ni][j];
        if (EPI == EPI_QKV) {
          Cb[idx] = f2bf(c + bval);
        } else if (EPI == EPI_SCE) {
          const float e = (col <= row) ? __expf(c * scale) : 0.f;
          Cb[idx] = f2bf(e);
        } else if (EPI == EPI_FF1) {
          const float r = c + bval;
          Cb[idx] = f2bf(r > 0.f ? r : 0.f);
        } else {  // EPI_PART
          Cf[idx] = c;
        }
      }
    }
  }
}

// ---------------------------------------------------------------------------
__global__ void normalize_rows(const unsigned short* __restrict__ attnb,
                               float* __restrict__ attnf,
                               float* __restrict__ rowsum) {
  const int m = blockIdx.x;
  const int tid = threadIdx.x;
  const int valid = m + 1;
  const unsigned short* rowb = attnb + (size_t)m * S;
  float* rowf = attnf + (size_t)m * S;

  float v[4][4];
  float lsum = 0.f;
  #pragma unroll
  for (int i = 0; i < 4; ++i) {
    const int idx = tid * 4 + i * 1024;
    #pragma unroll
    for (int j = 0; j < 4; ++j) v[i][j] = 0.f;
    if (i * 1024 <= m) {
      us4 b = *(const us4*)(rowb + idx);
      #pragma unroll
      for (int j = 0; j < 4; ++j) {
        const float e = (idx + j < valid) ? bf2f(b[j]) : 0.f;
        v[i][j] = e;
        lsum += e;
      }
    }
  }
  #pragma unroll
  for (int off = 32; off > 0; off >>= 1)
    lsum += __shfl_xor(lsum, off, 64);

  __shared__ float red[4];
  if ((tid & 63) == 0) red[tid >> 6] = lsum;
  __syncthreads();
  const float total = red[0] + red[1] + red[2] + red[3];
  if (tid == 0) rowsum[m] = total;
  const float inv = 1.0f / total;

  #pragma unroll
  for (int i = 0; i < 4; ++i) {
    const int idx = tid * 4 + i * 1024;
    f32x4 o;
    #pragma unroll
    for (int j = 0; j < 4; ++j) o[j] = v[i][j] * inv;
    *(f32x4*)(rowf + idx) = o;
  }
}

// ---------------------------------------------------------------------------
template <bool FINAL, bool NORM>
__global__ void reduce_k(const float* __restrict__ P,
                         const float* __restrict__ res,
                         const float* __restrict__ bias,
                         const float* __restrict__ rowsum,
                         float* __restrict__ outf,
                         unsigned short* __restrict__ outb, long n) {
  long i = ((long)blockIdx.x * 256 + threadIdx.x) * 4;
  if (i >= n) return;
  f32x4 a = *(const f32x4*)(P + i);
  f32x4 b = *(const f32x4*)(P + n + i);
  f32x4 r = *(const f32x4*)(res + i);
  float inv = 1.f;
  if (NORM) inv = 1.0f / rowsum[i >> 10];   // DM = 1024 elems per row
  if (FINAL) {
    f32x4 bb = *(const f32x4*)(bias + (i & (DM - 1)));
    f32x4 o;
    #pragma unroll
    for (int j = 0; j < 4; ++j) o[j] = a[j] + b[j] + r[j] + bb[j];
    *(f32x4*)(outf + i) = o;
  } else {
    f32x4 o; us4 ob;
    #pragma unroll
    for (int j = 0; j < 4; ++j) {
      o[j] = (a[j] + b[j]) * inv + r[j];
      ob[j] = f2bf(o[j]);
    }
    *(f32x4*)(outf + i) = o;
    *(us4*)(outb + i) = ob;
  }
}

// ---------------------------------------------------------------------------
extern "C" void kernel_launch(void* const* d_in, const int* in_sizes, int n_in,
                              void* d_out, int out_size, void* d_ws, size_t ws_size,
                              hipStream_t stream) {
  const float* x  = (const float*)d_in[0];
  const float* Wq = (const float*)d_in[1];
  const float* bq = (const float*)d_in[2];
  const float* Wk = (const float*)d_in[3];
  const float* bk = (const float*)d_in[4];
  const float* Wv = (const float*)d_in[5];
  const float* bv = (const float*)d_in[6];
  const float* W1 = (const float*)d_in[7];
  const float* b1 = (const float*)d_in[8];
  const float* W2 = (const float*)d_in[9];
  const float* b2 = (const float*)d_in[10];
  (void)in_sizes; (void)n_in; (void)out_size; (void)ws_size;

  float* outp  = (float*)d_out;                       // [S, DM]
  float* attnf = (float*)d_out + (size_t)S * DM;      // [S, S]

  const size_t MB = 1ull << 20;
  char* ws = (char*)d_ws;
  unsigned short* W2t   = (unsigned short*)(ws + 0 * MB);    // [DM,DI]  1->7
  unsigned short* W1t   = (unsigned short*)(ws + 8 * MB);    // [DI,DM]  1->6
  float*          h     = (float*)(ws + 16 * MB);            // [S,DM]   5->7
  unsigned short* hb    = (unsigned short*)(ws + 32 * MB);   // [S,DM]   5->6
  unsigned short* vt    = (unsigned short*)(ws + 40 * MB);   // [DM,S]   2->5
  unsigned short* attnb = (unsigned short*)(ws + 48 * MB);   // [S,S]    3->5
  unsigned short* qkv   = (unsigned short*)(ws + 80 * MB);   // [S,3072] 2->3
  unsigned short* xb    = (unsigned short*)(ws + 104 * MB);  // [S,DM]   1->2
  unsigned short* Wqkvt = (unsigned short*)(ws + 112 * MB);  // [3072,DM]1->2
  float*          bqkv  = (float*)(ws + 118 * MB);           // [3072]   1->2
  float*          rowsum= (float*)(ws + 119 * MB);           // [S]      4->5
  unsigned short* ff1b  = (unsigned short*)(ws + 40 * MB);   // [S,DI]   6->7
  float*          Ppv   = (float*)(ws + 80 * MB);            // [2][S,DM] ph5
  float*          Pff   = (float*)(ws + 72 * MB);            // [2][S,DM] ph7

  // --- phase 1: fused prep
  prep_all<<<dim3(13315), 256, 0, stream>>>(
      x, Wq, Wk, Wv, W1, W2, bq, bk, bv, xb, Wqkvt, W1t, W2t, bqkv);

  // --- phase 2: fused QKV projection (16x12 = 192 blocks), then v -> vt
  gemm8p<EPI_QKV, false, false><<<dim3((S / 256) * (3072 / 256), 1, 1), 512, 0, stream>>>(
      xb, Wqkvt, S, 3072, DM, DM, DM, DM, 3072 / 256, bqkv, nullptr, qkv, 1.f);
  transpose_bf16<<<dim3(DM / 32, S / 32), dim3(32, 8), 0, stream>>>(
      qkv + 2 * DM, 3072, vt, S);

  // --- phase 3: e = exp(q@k^T/32) bf16 (packed lower-tri, 136 blocks)
  gemm8p<EPI_SCE, true, false><<<dim3(136, 1, 1), 512, 0, stream>>>(
      qkv, qkv + DM, S, S, DM, 3072, 3072, DM, 0, nullptr, nullptr, attnb, 0.03125f);

  // --- phase 4: rowsum + fp32 attn into d_out
  normalize_rows<<<dim3(S), 256, 0, stream>>>(attnb, attnf, rowsum);

  // --- phase 5: attended = (e @ v)/rowsum (tri-truncated, split-K=2)
  gemm8p<EPI_PART, false, true><<<dim3((S / 256) * (DM / 256), 1, 2), 512, 0, stream>>>(
      attnb, vt, S, DM, S, S, S, S / 2, DM / 256, nullptr, Ppv, nullptr, 1.f);
  reduce_k<false, true><<<dim3((S * DM) / 1024), 256, 0, stream>>>(
      Ppv, x, nullptr, rowsum, h, hb, (long)S * DM);

  // --- phase 6: ff1 = relu(h @ W1 + b1) (16x16 = 256 blocks)
  gemm8p<EPI_FF1, false, false><<<dim3((S / 256) * (DI / 256), 1, 1), 512, 0, stream>>>(
      hb, W1t, S, DI, DM, DM, DM, DM, DI / 256, b1, nullptr, ff1b, 1.f);

  // --- phase 7: out = h + ff1 @ W2 + b2 (split-K=2) + final reduce
  gemm8p<EPI_PART, false, false><<<dim3((S / 256) * (DM / 256), 1, 2), 512, 0, stream>>>(
      ff1b, W2t, S, DM, DI, DI, DI, DI / 2, DM / 256, nullptr, Pff, nullptr, 1.f);
  reduce_k<true, false><<<dim3((S * DM) / 1024), 256, 0, stream>>>(
      Pff, h, b2, nullptr, outp, nullptr, (long)S * DM);
}

// Round 18
// 239.118 us; speedup vs baseline: 1.2035x; 1.2035x over previous
//
#include <hip/hip_runtime.h>
#include <hip/hip_bf16.h>

// ---------------------------------------------------------------------------
// TransformerLayer on MI355X (gfx950). Round 18: revert to measured-best R15
// GEMM (128x128, BK=64 dbuf-2, single barrier + vmcnt(0)/step, XCD remap +
// bn panels) + fuse the v-transpose into the QKV epilogue (v-slice tiles
// write vt[col*S+row] directly; transpose_bf16 dispatch deleted). Attn path:
// bf16 unnormalized-exp + normalize_rows + rowsum-divide (R12+).
// ---------------------------------------------------------------------------

typedef __attribute__((ext_vector_type(4))) float  f32x4;
typedef __attribute__((ext_vector_type(8))) short  bf16x8;
typedef __attribute__((ext_vector_type(4))) unsigned short us4;
typedef __attribute__((ext_vector_type(8))) unsigned short us8;

#define DEVINL __device__ __forceinline__

static constexpr int S   = 4096;
static constexpr int DM  = 1024;
static constexpr int DI  = 4096;

DEVINL unsigned short f2bf(float f) {
  union { float f; unsigned u; } v; v.f = f;
  unsigned r = v.u + 0x7fffu + ((v.u >> 16) & 1u);   // RNE
  return (unsigned short)(r >> 16);
}

DEVINL float bf2f(unsigned short b) {
  union { unsigned u; float f; } v; v.u = ((unsigned)b) << 16;
  return v.f;
}

DEVINL void gld_lds16(const unsigned short* g, unsigned short* l) {
  __builtin_amdgcn_global_load_lds(
      (const __attribute__((address_space(1))) void*)g,
      (__attribute__((address_space(3))) void*)l,
      16, 0, 0);
}

// bijective XCD remap (m204)
DEVINL int xcd_remap(int orig, int nwg) {
  const int q = nwg >> 3, r = nwg & 7;
  const int x = orig & 7, idx = orig >> 3;
  return (x < r ? x * (q + 1) : r * (q + 1) + (x - r) * q) + idx;
}

// ---------------------------------------------------------------------------
// Fused prep (unchanged from R13)
// ---------------------------------------------------------------------------
__global__ void prep_all(const float* __restrict__ x,
                         const float* __restrict__ Wq,
                         const float* __restrict__ Wk,
                         const float* __restrict__ Wv,
                         const float* __restrict__ W1,
                         const float* __restrict__ W2,
                         const float* __restrict__ bq,
                         const float* __restrict__ bk,
                         const float* __restrict__ bv,
                         unsigned short* __restrict__ xb,
                         unsigned short* __restrict__ Wqkvt,
                         unsigned short* __restrict__ W1t,
                         unsigned short* __restrict__ W2t,
                         float* __restrict__ bqkv) {
  __shared__ float tile[32][33];
  const int b = blockIdx.x;
  const int tid = threadIdx.x;

  if (b < 2048) {                       // x -> xb
    long i = ((long)b * 256 + tid) * 8;
    f32x4 a = *(const f32x4*)(x + i);
    f32x4 c = *(const f32x4*)(x + i + 4);
    us8 o;
    o[0] = f2bf(a[0]); o[1] = f2bf(a[1]); o[2] = f2bf(a[2]); o[3] = f2bf(a[3]);
    o[4] = f2bf(c[0]); o[5] = f2bf(c[1]); o[6] = f2bf(c[2]); o[7] = f2bf(c[3]);
    *(us8*)(xb + i) = o;
    return;
  }
  if (b >= 13312) {                     // bias concat
    const int t = b - 13312;
    const float* src = (t == 0) ? bq : (t == 1) ? bk : bv;
    const int i = tid * 4;
    *(f32x4*)(bqkv + t * DM + i) = *(const f32x4*)(src + i);
    return;
  }

  const float* in; unsigned short* out; int R, C, t;
  if (b < 3072)      { in = Wq; out = Wqkvt;                      R = DM; C = DM; t = b - 2048; }
  else if (b < 4096) { in = Wk; out = Wqkvt + (size_t)DM * DM;    R = DM; C = DM; t = b - 3072; }
  else if (b < 5120) { in = Wv; out = Wqkvt + 2 * (size_t)DM * DM;R = DM; C = DM; t = b - 4096; }
  else if (b < 9216) { in = W1; out = W1t;                        R = DM; C = DI; t = b - 5120; }
  else               { in = W2; out = W2t;                        R = DI; C = DM; t = b - 9216; }
  const int gx = C >> 5;
  const int bx = (t % gx) * 32, by = (t / gx) * 32;
  const int tx = tid & 31, ty = tid >> 5;     // 32 x 8
  #pragma unroll
  for (int j = 0; j < 4; ++j) {
    int r = ty + j * 8;
    tile[r][tx] = in[(size_t)(by + r) * C + bx + tx];
  }
  __syncthreads();
  #pragma unroll
  for (int j = 0; j < 4; ++j) {
    int r = ty + j * 8;
    out[(size_t)(bx + r) * R + by + tx] = f2bf(tile[tx][r]);
  }
}

// ---------------------------------------------------------------------------
// 128x128 tile, BK=64 K-steps, 256 thr (4 waves, 2Mx2N), dbuf=2 (64 KB LDS:
// per buf 4 panels [128][32] = A_k0|A_k1|B_k0|B_k1). One s_barrier + one
// post-compute vmcnt(0) per K-step. XCD remap + bn panels.
// EPI_QKV: v-slice tiles (bn0 >= 2048) write vt[(col-2048)*S + row] directly.
// C = A[M,K](lda) @ Bt[N,K](ldb)^T.
// ---------------------------------------------------------------------------
enum { EPI_QKV = 0, EPI_SCE = 1, EPI_FF1 = 4, EPI_PART = 6 };

#define VM_WAIT0 asm volatile("s_waitcnt vmcnt(0)" ::: "memory")

template <int EPI, bool TRI_PACK, bool TRI_TRUNC>
__launch_bounds__(256, 2)
__global__ void gemm4(const unsigned short* __restrict__ A,
                      const unsigned short* __restrict__ Bt,
                      int M, int N, int K, int lda, int ldb, int kChunk, int GX,
                      const float* __restrict__ bias,
                      float* __restrict__ Cf,
                      unsigned short* __restrict__ Cb,
                      unsigned short* __restrict__ vtp,
                      float scale) {
  const int wg = xcd_remap(blockIdx.x, gridDim.x);
  int bm, bn;
  if (TRI_PACK) {
    int t = wg;
    bm = (int)((sqrtf(8.f * (float)t + 1.f) - 1.f) * 0.5f);
    while ((bm + 1) * (bm + 2) / 2 <= t) ++bm;
    while (bm * (bm + 1) / 2 > t) --bm;
    bn = t - bm * (bm + 1) / 2;
  } else {
    const int GY_ = gridDim.x / GX;
    const int bpp = GY_ * 8;
    const int panel = wg / bpp, rem = wg % bpp;
    bm = rem >> 3;
    bn = panel * 8 + (rem & 7);
  }
  const int bm0 = bm * 128, bn0 = bn * 128;

  const int kbeg = blockIdx.z * kChunk;
  int kend = min(K, kbeg + kChunk);
  if (TRI_TRUNC) kend = min(kend, bm0 + 128);
  const int len = kend - kbeg;
  const int NT = (len > 0) ? (len >> 6) : 0;   // BK=64 steps

  // 2 bufs x 4 panels x [128][32] bf16 (8 KB each) = 64 KB
  __shared__ __align__(16) unsigned short lds[2 * 16384];

  const int tid  = threadIdx.x;
  const int lane = tid & 63;
  const int w    = tid >> 6;                  // wave 0..3
  const int wr   = w >> 1, wc = w & 1;        // 2 x 2 wave grid
  const int fr   = lane & 15, fq = lane >> 4;

  f32x4 acc[4][4] = {};

  const int tq = tid >> 2;                               // row 0..63
  const int swcolE = ((tid & 3) * 8) ^ ((tq & 6) << 2);  // swizzled col in K32
  const unsigned short* gA = A  + (size_t)(bm0 + tq) * lda + kbeg + swcolE;
  const unsigned short* gB = Bt + (size_t)(bn0 + tq) * ldb + kbeg + swcolE;
  const size_t aH = (size_t)64 * lda, bH = (size_t)64 * ldb;

  auto stage = [&](int buf, int t_) {        // 8 gld_lds per thread (BK=64)
    unsigned short* base = (unsigned short*)lds + buf * 16384;
    const size_t go = (size_t)t_ * 64;
    #pragma unroll
    for (int ks = 0; ks < 2; ++ks) {
      const size_t gk = go + ks * 32;
      gld_lds16(gA + gk,      base + ks * 4096 + w * 512);          // A rows 0-63
      gld_lds16(gA + aH + gk, base + ks * 4096 + 2048 + w * 512);   // A rows 64-127
      gld_lds16(gB + gk,      base + 8192 + ks * 4096 + w * 512);   // B rows 0-63
      gld_lds16(gB + bH + gk, base + 8192 + ks * 4096 + 2048 + w * 512);
    }
  };

  const int frSw = (fq * 8) ^ ((fr & 6) << 2);
  auto rdA = [&](int buf, int ks, int mi) {
    return *(const bf16x8*)((const unsigned short*)lds + buf * 16384 + ks * 4096 +
                            (wr * 64 + mi * 16 + fr) * 32 + frSw);
  };
  auto rdB = [&](int buf, int ks, int ni) {
    return *(const bf16x8*)((const unsigned short*)lds + buf * 16384 + 8192 + ks * 4096 +
                            (wc * 64 + ni * 16 + fr) * 32 + frSw);
  };

  if (NT > 0) {
    stage(0, 0);
    VM_WAIT0;
    __builtin_amdgcn_s_barrier();

    for (int t = 0; t < NT; ++t) {
      const int cur = t & 1, nxt = cur ^ 1;
      const bool pf = (t + 1 < NT);
      if (pf) stage(nxt, t + 1);     // 8 loads in flight under the compute

      #pragma unroll
      for (int ks = 0; ks < 2; ++ks) {
        bf16x8 a[4], b[4];
        #pragma unroll
        for (int mi = 0; mi < 4; ++mi) a[mi] = rdA(cur, ks, mi);
        #pragma unroll
        for (int ni = 0; ni < 4; ++ni) b[ni] = rdB(cur, ks, ni);
        #pragma unroll
        for (int mi = 0; mi < 4; ++mi)
          #pragma unroll
          for (int ni = 0; ni < 4; ++ni)
            acc[mi][ni] = __builtin_amdgcn_mfma_f32_16x16x32_bf16(
                a[mi], b[ni], acc[mi][ni], 0, 0, 0);
      }

      if (pf) { VM_WAIT0; }
      __builtin_amdgcn_s_barrier();
    }
  }

  // ---- epilogue: C/D layout col = lane&15, row = (lane>>4)*4 + reg ----
  const int row0 = bm0 + wr * 64 + fq * 4;
  const int col0 = bn0 + wc * 64 + fr;
  const size_t zoff = (EPI == EPI_PART) ? (size_t)blockIdx.z * M * N : 0;
  const bool vtile = (EPI == EPI_QKV) && (bn0 >= 2048);   // whole tile is v
  #pragma unroll
  for (int ni = 0; ni < 4; ++ni) {
    const int col = col0 + ni * 16;
    float bval = 0.f;
    if (EPI == EPI_QKV || EPI == EPI_FF1) bval = bias[col];
    #pragma unroll
    for (int mi = 0; mi < 4; ++mi) {
      if (vtile) {
        // transposed v write: vt[(col-2048)*S + row], 4 consecutive rows
        us4 ob;
        #pragma unroll
        for (int j = 0; j < 4; ++j) ob[j] = f2bf(acc[mi][ni][j] + bval);
        *(us4*)(vtp + (size_t)(col - 2048) * S + row0 + mi * 16) = ob;
      } else {
        #pragma unroll
        for (int j = 0; j < 4; ++j) {
          const int row = row0 + mi * 16 + j;
          const size_t idx = zoff + (size_t)row * N + col;
          const float c = acc[mi][ni][j];
          if (EPI == EPI_QKV) {
            Cb[idx] = f2bf(c + bval);
          } else if (EPI == EPI_SCE) {
            const float e = (col <= row) ? __expf(c * scale) : 0.f;
            Cb[idx] = f2bf(e);
          } else if (EPI == EPI_FF1) {
            const float r = c + bval;
            Cb[idx] = f2bf(r > 0.f ? r : 0.f);
          } else {  // EPI_PART
            Cf[idx] = c;
          }
        }
      }
    }
  }
}

// ---------------------------------------------------------------------------
__global__ void normalize_rows(const unsigned short* __restrict__ attnb,
                               float* __restrict__ attnf,
                               float* __restrict__ rowsum) {
  const int m = blockIdx.x;
  const int tid = threadIdx.x;
  const int valid = m + 1;
  const unsigned short* rowb = attnb + (size_t)m * S;
  float* rowf = attnf + (size_t)m * S;

  float v[4][4];
  float lsum = 0.f;
  #pragma unroll
  for (int i = 0; i < 4; ++i) {
    const int idx = tid * 4 + i * 1024;
    #pragma unroll
    for (int j = 0; j < 4; ++j) v[i][j] = 0.f;
    if (i * 1024 <= m) {
      us4 b = *(const us4*)(rowb + idx);
      #pragma unroll
      for (int j = 0; j < 4; ++j) {
        const float e = (idx + j < valid) ? bf2f(b[j]) : 0.f;
        v[i][j] = e;
        lsum += e;
      }
    }
  }
  #pragma unroll
  for (int off = 32; off > 0; off >>= 1)
    lsum += __shfl_xor(lsum, off, 64);

  __shared__ float red[4];
  if ((tid & 63) == 0) red[tid >> 6] = lsum;
  __syncthreads();
  const float total = red[0] + red[1] + red[2] + red[3];
  if (tid == 0) rowsum[m] = total;
  const float inv = 1.0f / total;

  #pragma unroll
  for (int i = 0; i < 4; ++i) {
    const int idx = tid * 4 + i * 1024;
    f32x4 o;
    #pragma unroll
    for (int j = 0; j < 4; ++j) o[j] = v[i][j] * inv;
    *(f32x4*)(rowf + idx) = o;
  }
}

// ---------------------------------------------------------------------------
template <bool FINAL, bool NORM>
__global__ void reduce_k(const float* __restrict__ P,
                         const float* __restrict__ res,
                         const float* __restrict__ bias,
                         const float* __restrict__ rowsum,
                         float* __restrict__ outf,
                         unsigned short* __restrict__ outb, long n) {
  long i = ((long)blockIdx.x * 256 + threadIdx.x) * 4;
  if (i >= n) return;
  f32x4 a = *(const f32x4*)(P + i);
  f32x4 b = *(const f32x4*)(P + n + i);
  f32x4 r = *(const f32x4*)(res + i);
  float inv = 1.f;
  if (NORM) inv = 1.0f / rowsum[i >> 10];   // DM = 1024 elems per row
  if (FINAL) {
    f32x4 bb = *(const f32x4*)(bias + (i & (DM - 1)));
    f32x4 o;
    #pragma unroll
    for (int j = 0; j < 4; ++j) o[j] = a[j] + b[j] + r[j] + bb[j];
    *(f32x4*)(outf + i) = o;
  } else {
    f32x4 o; us4 ob;
    #pragma unroll
    for (int j = 0; j < 4; ++j) {
      o[j] = (a[j] + b[j]) * inv + r[j];
      ob[j] = f2bf(o[j]);
    }
    *(f32x4*)(outf + i) = o;
    *(us4*)(outb + i) = ob;
  }
}

// ---------------------------------------------------------------------------
extern "C" void kernel_launch(void* const* d_in, const int* in_sizes, int n_in,
                              void* d_out, int out_size, void* d_ws, size_t ws_size,
                              hipStream_t stream) {
  const float* x  = (const float*)d_in[0];
  const float* Wq = (const float*)d_in[1];
  const float* bq = (const float*)d_in[2];
  const float* Wk = (const float*)d_in[3];
  const float* bk = (const float*)d_in[4];
  const float* Wv = (const float*)d_in[5];
  const float* bv = (const float*)d_in[6];
  const float* W1 = (const float*)d_in[7];
  const float* b1 = (const float*)d_in[8];
  const float* W2 = (const float*)d_in[9];
  const float* b2 = (const float*)d_in[10];
  (void)in_sizes; (void)n_in; (void)out_size; (void)ws_size;

  float* outp  = (float*)d_out;                       // [S, DM]
  float* attnf = (float*)d_out + (size_t)S * DM;      // [S, S]

  const size_t MB = 1ull << 20;
  char* ws = (char*)d_ws;
  unsigned short* W2t   = (unsigned short*)(ws + 0 * MB);    // [DM,DI]  1->7
  unsigned short* W1t   = (unsigned short*)(ws + 8 * MB);    // [DI,DM]  1->6
  float*          h     = (float*)(ws + 16 * MB);            // [S,DM]   5->7
  unsigned short* hb    = (unsigned short*)(ws + 32 * MB);   // [S,DM]   5->6
  unsigned short* vt    = (unsigned short*)(ws + 40 * MB);   // [DM,S]   2->5
  unsigned short* attnb = (unsigned short*)(ws + 48 * MB);   // [S,S]    3->5
  unsigned short* qkv   = (unsigned short*)(ws + 80 * MB);   // [S,3072] 2->3
  unsigned short* xb    = (unsigned short*)(ws + 104 * MB);  // [S,DM]   1->2
  unsigned short* Wqkvt = (unsigned short*)(ws + 112 * MB);  // [3072,DM]1->2
  float*          bqkv  = (float*)(ws + 118 * MB);           // [3072]   1->2
  float*          rowsum= (float*)(ws + 119 * MB);           // [S]      4->5
  unsigned short* ff1b  = (unsigned short*)(ws + 40 * MB);   // [S,DI]   6->7
  float*          Ppv   = (float*)(ws + 80 * MB);            // [2][S,DM] ph5
  float*          Pff   = (float*)(ws + 72 * MB);            // [2][S,DM] ph7

  // --- phase 1: fused prep
  prep_all<<<dim3(13315), 256, 0, stream>>>(
      x, Wq, Wk, Wv, W1, W2, bq, bk, bv, xb, Wqkvt, W1t, W2t, bqkv);

  // --- phase 2: fused QKV projection (768 blocks); v-slice written to vt
  gemm4<EPI_QKV, false, false><<<dim3((S / 128) * (3072 / 128), 1, 1), 256, 0, stream>>>(
      xb, Wqkvt, S, 3072, DM, DM, DM, DM, 3072 / 128, bqkv, nullptr, qkv, vt, 1.f);

  // --- phase 3: e = exp(q@k^T/32) bf16 (packed lower-tri, 528 blocks)
  gemm4<EPI_SCE, true, false><<<dim3(528, 1, 1), 256, 0, stream>>>(
      qkv, qkv + DM, S, S, DM, 3072, 3072, DM, 0, nullptr, nullptr, attnb, nullptr, 0.03125f);

  // --- phase 4: rowsum + fp32 attn into d_out
  normalize_rows<<<dim3(S), 256, 0, stream>>>(attnb, attnf, rowsum);

  // --- phase 5: attended = (e @ v)/rowsum (tri-truncated, split-K=2)
  gemm4<EPI_PART, false, true><<<dim3((S / 128) * (DM / 128), 1, 2), 256, 0, stream>>>(
      attnb, vt, S, DM, S, S, S, S / 2, DM / 128, nullptr, Ppv, nullptr, nullptr, 1.f);
  reduce_k<false, true><<<dim3((S * DM) / 1024), 256, 0, stream>>>(
      Ppv, x, nullptr, rowsum, h, hb, (long)S * DM);

  // --- phase 6: ff1 = relu(h @ W1 + b1) (1024 blocks)
  gemm4<EPI_FF1, false, false><<<dim3((S / 128) * (DI / 128), 1, 1), 256, 0, stream>>>(
      hb, W1t, S, DI, DM, DM, DM, DM, DI / 128, b1, nullptr, ff1b, nullptr, 1.f);

  // --- phase 7: out = h + ff1 @ W2 + b2 (split-K=2) + final reduce
  gemm4<EPI_PART, false, false><<<dim3((S / 128) * (DM / 128), 1, 2), 256, 0, stream>>>(
      ff1b, W2t, S, DM, DI, DI, DI, DI / 2, DM / 128, nullptr, Pff, nullptr, nullptr, 1.f);
  reduce_k<true, false><<<dim3((S * DM) / 1024), 256, 0, stream>>>(
      Pff, h, b2, nullptr, outp, nullptr, (long)S * DM);
}